// Round 8
// baseline (345.875 us; speedup 1.0000x reference)
//
#include <hip/hip_runtime.h>

#define DIM 64
#define PRESERVE 0.1f

typedef unsigned short bf16_t;

__device__ __forceinline__ float readlane_f(float v, int l) {
    return __int_as_float(__builtin_amdgcn_readlane(__float_as_int(v), l));
}
__device__ __forceinline__ float bf2f(bf16_t u) {
    return __uint_as_float(((unsigned)u) << 16);
}
__device__ __forceinline__ bf16_t f2bf(float f) {
    unsigned u = __float_as_uint(f);
    unsigned r = (u + 0x7FFFu + ((u >> 16) & 1u)) >> 16;  // RNE
    return (bf16_t)r;
}

// ---------- init ----------
__global__ void k_init(int* cursor, int n) {
    int i = blockIdx.x * blockDim.x + threadIdx.x;
    if (i < n) cursor[i] = 0;
}

// ---------- FUSED: histogram+rank (1/3 of blocks) || xs1 = bf16(x@W1) (2/3) ----------
// hist is atomic-latency-bound (VALUBusy ~0.3%): mm rides the idle VALU pipes.
__global__ __launch_bounds__(256) void k_hist_mm(
        const int* __restrict__ col, int* __restrict__ cursor,
        int* __restrict__ rank, int E,
        const float* __restrict__ x, const float* __restrict__ W,
        bf16_t* __restrict__ xs, int n) {
    int bid = blockIdx.x;
    int G = gridDim.x;
    if (bid % 3 == 0) {
        // ---- hist role ----
        int hb = bid / 3;
        int nhb = (G + 2) / 3;
        int tid0 = hb * 256 + threadIdx.x;
        int nthreads = nhb * 256;
        int nvec = E >> 2;
        const int4* col4 = (const int4*)col;
        int4* rank4 = (int4*)rank;
        for (int t = tid0; t < nvec; t += nthreads) {
            int4 c = col4[t];
            int4 r;
            r.x = atomicAdd(&cursor[c.x], 1);
            r.y = atomicAdd(&cursor[c.y], 1);
            r.z = atomicAdd(&cursor[c.z], 1);
            r.w = atomicAdd(&cursor[c.w], 1);
            rank4[t] = r;
        }
        for (int e = (nvec << 2) + tid0; e < E; e += nthreads)
            rank[e] = atomicAdd(&cursor[col[e]], 1);
    } else {
        // ---- mm role: xs = bf16(x @ W), no dinv ----
        int mb = bid - (bid / 3) - 1;      // dense id among non-hist blocks
        int nmb = G - (G + 2) / 3;
        int lane = threadIdx.x & 63;
        int waveId = mb * 4 + (threadIdx.x >> 6);
        int nWaves = nmb * 4;
        float Wr[DIM];
#pragma unroll
        for (int k = 0; k < DIM; ++k) Wr[k] = W[k * DIM + lane];
        for (int r0 = waveId * 4; r0 < n; r0 += nWaves * 4) {
            if (r0 + 3 < n) {
                float x0 = x[(size_t)(r0 + 0) * DIM + lane];
                float x1 = x[(size_t)(r0 + 1) * DIM + lane];
                float x2 = x[(size_t)(r0 + 2) * DIM + lane];
                float x3 = x[(size_t)(r0 + 3) * DIM + lane];
                float a0 = 0.f, a1 = 0.f, a2 = 0.f, a3 = 0.f;
#pragma unroll
                for (int k = 0; k < DIM; ++k) {
                    float w = Wr[k];
                    a0 += readlane_f(x0, k) * w;
                    a1 += readlane_f(x1, k) * w;
                    a2 += readlane_f(x2, k) * w;
                    a3 += readlane_f(x3, k) * w;
                }
                xs[(size_t)(r0 + 0) * DIM + lane] = f2bf(a0);
                xs[(size_t)(r0 + 1) * DIM + lane] = f2bf(a1);
                xs[(size_t)(r0 + 2) * DIM + lane] = f2bf(a2);
                xs[(size_t)(r0 + 3) * DIM + lane] = f2bf(a3);
            } else {
                for (int r = r0; r < n; ++r) {
                    float xv = x[(size_t)r * DIM + lane];
                    float a = 0.f;
#pragma unroll
                    for (int k = 0; k < DIM; ++k) a += readlane_f(xv, k) * Wr[k];
                    xs[(size_t)r * DIM + lane] = f2bf(a);
                }
            }
        }
    }
}

// ---------- 2-level exclusive scan of counts(=cursor) -> offsets ----------
__global__ __launch_bounds__(256) void k_scan1(const int* __restrict__ counts,
                                               int* __restrict__ offsets,
                                               int* __restrict__ blksum, int n) {
    __shared__ int s[256];
    int t = threadIdx.x;
    int idx = blockIdx.x * 256 + t;
    int v = (idx < n) ? counts[idx] : 0;
    s[t] = v;
    __syncthreads();
    for (int off = 1; off < 256; off <<= 1) {
        int x = (t >= off) ? s[t - off] : 0;
        __syncthreads();
        s[t] += x;
        __syncthreads();
    }
    if (idx < n) offsets[idx] = s[t];
    if (t == 255) blksum[blockIdx.x] = s[255];
}

__global__ __launch_bounds__(512) void k_scan2(const int* __restrict__ blksum,
                                               int* __restrict__ blkoff, int nblk) {
    __shared__ int s[512];
    int t = threadIdx.x;
    int v = (t < nblk) ? blksum[t] : 0;
    s[t] = v;
    __syncthreads();
    for (int off = 1; off < 512; off <<= 1) {
        int x = (t >= off) ? s[t - off] : 0;
        __syncthreads();
        s[t] += x;
        __syncthreads();
    }
    if (t < nblk) blkoff[t] = s[t] - v;  // exclusive
}

__global__ __launch_bounds__(256) void k_scan3(const int* __restrict__ counts,
                                               int* __restrict__ offsets,
                                               const int* __restrict__ blkoff,
                                               int n, int E) {
    int t = threadIdx.x;
    int idx = blockIdx.x * 256 + t;
    if (idx < n) offsets[idx] = offsets[idx] - counts[idx] + blkoff[blockIdx.x];
    if (idx == 0) offsets[n] = E;
}

// ---------- bucket-fill CSR: sedge[offsets[col]+rank] = {row, w_raw} ----------
__global__ void k_fill4(const int4* __restrict__ row4, const int4* __restrict__ col4,
                        const float4* __restrict__ w4, const int4* __restrict__ rank4,
                        const int* __restrict__ offsets, int2* __restrict__ sedge,
                        int nthreads) {
    int t = blockIdx.x * blockDim.x + threadIdx.x;
    if (t >= nthreads) return;
    int4 r = row4[t];
    int4 c = col4[t];
    float4 w = w4[t];
    int4 k = rank4[t];
    int2 p;
    p.x = r.x; p.y = __float_as_int(w.x); sedge[offsets[c.x] + k.x] = p;
    p.x = r.y; p.y = __float_as_int(w.y); sedge[offsets[c.y] + k.y] = p;
    p.x = r.z; p.y = __float_as_int(w.z); sedge[offsets[c.z] + k.z] = p;
    p.x = r.w; p.y = __float_as_int(w.w); sedge[offsets[c.w] + k.w] = p;
}

__global__ void k_fill1(const int* __restrict__ row, const int* __restrict__ col,
                        const float* __restrict__ w, const int* __restrict__ rank,
                        const int* __restrict__ offsets, int2* __restrict__ sedge,
                        int E) {
    int e = blockIdx.x * blockDim.x + threadIdx.x;
    if (e >= E) return;
    int2 p;
    p.x = row[e];
    p.y = __float_as_int(w[e]);
    sedge[offsets[col[e]] + rank[e]] = p;
}

// ---------- deg -> dinv from CSR (wave per node, raw weights) ----------
__global__ __launch_bounds__(256) void k_deg_seg(const int2* __restrict__ sedge,
                                                 const int* __restrict__ offsets,
                                                 float* __restrict__ dinv, int n) {
    int tid = threadIdx.x;
    int lane = tid & 63;
    int c = blockIdx.x * 4 + (tid >> 6);
    if (c >= n) return;
    int beg = offsets[c];
    int end = offsets[c + 1];
    float s = 0.0f;
    for (int j = beg + lane; j < end; j += 64) s += __int_as_float(sedge[j].y);
    for (int off = 32; off > 0; off >>= 1) s += __shfl_xor(s, off);
    if (lane == 0) {
        float d = 1.0f + s;  // self-loop weight
        dinv[c] = (d > 0.0f) ? rsqrtf(d) : 0.0f;
    }
}

// ---------- fold source norm into edge weight: w' = w * dinv[row] ----------
__global__ void k_rescale(int2* sedge, const float* __restrict__ dinv, int E) {
    int e = blockIdx.x * blockDim.x + threadIdx.x;
    if (e >= E) return;
    int2 p = sedge[e];
    p.y = __float_as_int(__int_as_float(p.y) * dinv[p.x]);
    sedge[e] = p;
}

// ---------- gather1 + fused mm2 ----------
// temp[c] = 0.9*( di*(sum_e w'_e*xs1[r] + di*xs1[c]) + b1 ) + 0.1*x[c]
// xs2[c]  = bf16( temp[c] @ W2 )   (row-local, W2 in 64 VGPRs, grid-stride amortized)
__global__ __launch_bounds__(256) void k_gather_mm(
        const bf16_t* __restrict__ xs1, const int* __restrict__ offsets,
        const int2* __restrict__ sedge, const float* __restrict__ dinv,
        const float* __restrict__ b, const float* __restrict__ xprev,
        const float* __restrict__ W2, float* __restrict__ temp,
        bf16_t* __restrict__ xs2, int n) {
    int lane = threadIdx.x & 63;
    int waveId = blockIdx.x * 4 + (threadIdx.x >> 6);
    int nWaves = gridDim.x * 4;

    float W2r[DIM];
#pragma unroll
    for (int k = 0; k < DIM; ++k) W2r[k] = W2[k * DIM + lane];

    for (int c = waveId; c < n; c += nWaves) {
        float di = dinv[c];
        float acc = di * bf2f(xs1[(size_t)c * DIM + lane]);  // self-loop (×di again later)
        int beg = offsets[c];
        int end = offsets[c + 1];
        for (int b0 = beg; b0 < end; b0 += 64) {
            int m = end - b0;
            if (m > 64) m = 64;
            int r_l = 0, w_l = 0;
            if (lane < m) {
                int2 p = sedge[b0 + lane];
                r_l = p.x;
                w_l = p.y;
            }
            int j = 0;
            for (; j + 3 < m; j += 4) {
                int r0 = __builtin_amdgcn_readlane(r_l, j);
                int r1 = __builtin_amdgcn_readlane(r_l, j + 1);
                int r2 = __builtin_amdgcn_readlane(r_l, j + 2);
                int r3 = __builtin_amdgcn_readlane(r_l, j + 3);
                float w0 = readlane_f(__int_as_float(w_l), j);
                float w1 = readlane_f(__int_as_float(w_l), j + 1);
                float w2 = readlane_f(__int_as_float(w_l), j + 2);
                float w3 = readlane_f(__int_as_float(w_l), j + 3);
                acc += bf2f(xs1[(size_t)r0 * DIM + lane]) * w0;
                acc += bf2f(xs1[(size_t)r1 * DIM + lane]) * w1;
                acc += bf2f(xs1[(size_t)r2 * DIM + lane]) * w2;
                acc += bf2f(xs1[(size_t)r3 * DIM + lane]) * w3;
            }
            for (; j < m; ++j) {
                int r0 = __builtin_amdgcn_readlane(r_l, j);
                float w0 = readlane_f(__int_as_float(w_l), j);
                acc += bf2f(xs1[(size_t)r0 * DIM + lane]) * w0;
            }
        }
        float tv = (1.0f - PRESERVE) * (acc * di + b[lane])
                 + PRESERVE * xprev[(size_t)c * DIM + lane];
        temp[(size_t)c * DIM + lane] = tv;
        // fused mm2: xs2 row = tv @ W2
        float a = 0.f;
#pragma unroll
        for (int k = 0; k < DIM; ++k) a += readlane_f(tv, k) * W2r[k];
        xs2[(size_t)c * DIM + lane] = f2bf(a);
    }
}

// ---------- gather2 (final layer, writes d_out) ----------
__global__ __launch_bounds__(256) void k_gather2(
        const bf16_t* __restrict__ xs2, const int* __restrict__ offsets,
        const int2* __restrict__ sedge, const float* __restrict__ dinv,
        const float* __restrict__ b, const float* __restrict__ xprev,
        float* __restrict__ out, int n) {
    int lane = threadIdx.x & 63;
    int c = blockIdx.x * 4 + (threadIdx.x >> 6);
    if (c >= n) return;
    float di = dinv[c];
    float acc = di * bf2f(xs2[(size_t)c * DIM + lane]);
    int beg = offsets[c];
    int end = offsets[c + 1];
    for (int b0 = beg; b0 < end; b0 += 64) {
        int m = end - b0;
        if (m > 64) m = 64;
        int r_l = 0, w_l = 0;
        if (lane < m) {
            int2 p = sedge[b0 + lane];
            r_l = p.x;
            w_l = p.y;
        }
        int j = 0;
        for (; j + 3 < m; j += 4) {
            int r0 = __builtin_amdgcn_readlane(r_l, j);
            int r1 = __builtin_amdgcn_readlane(r_l, j + 1);
            int r2 = __builtin_amdgcn_readlane(r_l, j + 2);
            int r3 = __builtin_amdgcn_readlane(r_l, j + 3);
            float w0 = readlane_f(__int_as_float(w_l), j);
            float w1 = readlane_f(__int_as_float(w_l), j + 1);
            float w2 = readlane_f(__int_as_float(w_l), j + 2);
            float w3 = readlane_f(__int_as_float(w_l), j + 3);
            acc += bf2f(xs2[(size_t)r0 * DIM + lane]) * w0;
            acc += bf2f(xs2[(size_t)r1 * DIM + lane]) * w1;
            acc += bf2f(xs2[(size_t)r2 * DIM + lane]) * w2;
            acc += bf2f(xs2[(size_t)r3 * DIM + lane]) * w3;
        }
        for (; j < m; ++j) {
            int r0 = __builtin_amdgcn_readlane(r_l, j);
            float w0 = readlane_f(__int_as_float(w_l), j);
            acc += bf2f(xs2[(size_t)r0 * DIM + lane]) * w0;
        }
    }
    float v = (1.0f - PRESERVE) * (acc * di + b[lane])
            + PRESERVE * xprev[(size_t)c * DIM + lane];
    out[(size_t)c * DIM + lane] = v;
}

extern "C" void kernel_launch(void* const* d_in, const int* in_sizes, int n_in,
                              void* d_out, int out_size, void* d_ws, size_t ws_size,
                              hipStream_t stream) {
    const float* x  = (const float*)d_in[0];
    const int*   ei = (const int*)d_in[1];
    const float* ew = (const float*)d_in[2];
    const float* W1 = (const float*)d_in[3];
    const float* b1 = (const float*)d_in[4];
    const float* W2 = (const float*)d_in[5];
    const float* b2 = (const float*)d_in[6];

    const int N = in_sizes[0] / DIM;      // 100000
    const int E = in_sizes[2];            // 1250000
    const int* row = ei;
    const int* col = ei + E;

    // workspace layout
    int2* sedge   = (int2*)d_ws;                          // E (8B-aligned)
    float* dinv   = (float*)(sedge + E);                  // N
    float* temp   = dinv + N;                             // N*DIM fp32
    bf16_t* xs1   = (bf16_t*)(temp + (size_t)N * DIM);    // N*DIM bf16
    bf16_t* xs2   = xs1 + (size_t)N * DIM;                // N*DIM bf16
    // rank+cursor overlay xs2's region: rank/cursor dead before xs2 is written
    int* rank     = (int*)xs2;                            // E (5 MB < 12.8 MB)
    int* cursor   = rank + E;                             // N
    int* offsets  = (int*)(xs2 + (size_t)N * DIM);        // N+1 (survives to gather2)
    int* blksum   = offsets + N + 1;                      // <=640
    int* blkoff   = blksum + 640;                         // <=640

    const int B = 256;
    const int nblkN = (N + B - 1) / B;   // 391 (<=512 for k_scan2)
    const int nblkG = (N + 3) / 4;
    const int G2 = 1536;                 // 512 hist blocks + 1024 mm blocks
    const int nblkGM = 1024;             // gather1+mm2 grid-stride

    k_init<<<nblkN, B, 0, stream>>>(cursor, N);

    // fused: histogram+rank || xs1 = bf16(x @ W1)
    k_hist_mm<<<G2, B, 0, stream>>>(col, cursor, rank, E, x, W1, xs1, N);

    // scan counts -> offsets
    k_scan1<<<nblkN, B, 0, stream>>>(cursor, offsets, blksum, N);
    k_scan2<<<1, 512, 0, stream>>>(blksum, blkoff, nblkN);
    k_scan3<<<nblkN, B, 0, stream>>>(cursor, offsets, blkoff, N, E);

    // fill CSR (no atomics), raw weights
    if ((E & 3) == 0) {
        int nt = E / 4;
        k_fill4<<<(nt + B - 1) / B, B, 0, stream>>>((const int4*)row, (const int4*)col,
                                                    (const float4*)ew, (const int4*)rank,
                                                    offsets, sedge, nt);
    } else {
        k_fill1<<<(E + B - 1) / B, B, 0, stream>>>(row, col, ew, rank, offsets, sedge, E);
    }

    // dinv from segmented degree sum (raw w), then fold dinv[row] into weights
    k_deg_seg<<<nblkG, B, 0, stream>>>(sedge, offsets, dinv, N);
    k_rescale<<<(E + B - 1) / B, B, 0, stream>>>(sedge, dinv, E);

    // layer 1 gather (+ fused mm2 -> xs2), then layer 2 gather
    k_gather_mm<<<nblkGM, B, 0, stream>>>(xs1, offsets, sedge, dinv, b1, x,
                                          W2, temp, xs2, N);
    k_gather2<<<nblkG, B, 0, stream>>>(xs2, offsets, sedge, dinv, b2, temp,
                                       (float*)d_out, N);
}